// Round 1
// baseline (173.185 us; speedup 1.0000x reference)
//
#include <hip/hip_runtime.h>
#include <stdint.h>

// Problem constants
#define CC    1024
#define EE    320
#define KN    640         // G*E
#define DD    256
#define MTOT  16384       // B*T
#define NBLK  640         // GEMM grid
#define OUT4  2097152     // output float4 count
#define ZPB   3277        // zero-fill float4s per block (640*3277 >= OUT4)
#define MARGIN 2.0f       // candidate gate: 15 sigma of bf16 dropped-term error

typedef __attribute__((ext_vector_type(8))) short short8;
typedef __attribute__((ext_vector_type(4))) float f32x4;

__device__ __forceinline__ unsigned int f32_orderable(float x) {
    unsigned int b = __float_as_uint(x);
    return (b & 0x80000000u) ? ~b : (b | 0x80000000u);
}

__device__ __forceinline__ unsigned short bf16_rne(float x) {
    unsigned int u = __float_as_uint(x);
    return (unsigned short)((u + 0x7FFFu + ((u >> 16) & 1u)) >> 16);
}

__global__ void init_slots_kernel(unsigned long long* __restrict__ slots) {
    if (threadIdx.x < 17) slots[threadIdx.x] = 0ull;
}

// ------------------- prep: W -> bf16 frag-major (B2F) + slot/counter init -------------------
// Frag-major layout: unit = (row/16)*32 + (k/32);
//   B2F[unit*512 + lane*8 + j] = bf16 of W[unit_row*16 + (lane&15)][kc*32 + (lane>>4)*8 + j]
// Each 1KB unit is linear -> GEMM streams it with one global_load_lds (width 16) per wave.
__global__ __launch_bounds__(256)
void prep_kernel(const float* __restrict__ W, unsigned short* __restrict__ B2F,
                 unsigned long long* __restrict__ slots) {
    if (blockIdx.x == 0 && threadIdx.x < 17) slots[threadIdx.x] = 0ull;
    const int lane = threadIdx.x & 63;
    int unit = blockIdx.x * 4 + (threadIdx.x >> 6);     // 1280 units total
    int rt = unit >> 5, kc = unit & 31;
    int row = rt * 16 + (lane & 15);
    int col = kc * 32 + ((lane >> 4) << 3);
    const float* p = W + (size_t)row * CC + col;
    float4 v0 = *(const float4*)p;
    float4 v1 = *(const float4*)(p + 4);
    short8 hi;
    hi[0] = (short)bf16_rne(v0.x); hi[1] = (short)bf16_rne(v0.y);
    hi[2] = (short)bf16_rne(v0.z); hi[3] = (short)bf16_rne(v0.w);
    hi[4] = (short)bf16_rne(v1.x); hi[5] = (short)bf16_rne(v1.y);
    hi[6] = (short)bf16_rne(v1.z); hi[7] = (short)bf16_rne(v1.w);
    *(short8*)(B2F + (size_t)unit * 512 + lane * 8) = hi;
}

// ------------------- fused: zero-fill + fp32->bf16 staged MFMA GEMM + argmax + refine + scatter
// X is read fp32 ONCE: reg-staged, converted via v_cvt_pk_bf16_f32, ds_written frag-major.
// B streamed bf16 via global_load_lds. LDS double-buffered (2 x (8KB A + 8KB B)), one
// barrier per K-step. Epilogue identical to the verified margin-argmax/refine/scatter.
__global__ __launch_bounds__(256, 3)
void vq_fused(const float* __restrict__ X,
              const unsigned short* __restrict__ B2F,
              const float* __restrict__ W,
              const float* __restrict__ bias,
              const float* __restrict__ codebook,
              float* __restrict__ out,
              unsigned long long* __restrict__ slots,
              unsigned int* __restrict__ counter) {
    __shared__ __align__(16) unsigned short lds_s[16384];   // 32KB: 2 bufs x (A 4096 + B 4096)
    __shared__ float redf[4];
    __shared__ int cnt_s;
    __shared__ int cand_s[128];
    __shared__ unsigned int done_s;
    __shared__ unsigned long long s16[16];

    const int tid  = threadIdx.x;
    const int lane = tid & 63;
    const int wave = tid >> 6;

    // XCD swizzle: one XCD covers 16 m-tiles x all 5 n-tiles (n fastest) -> X L2 reuse.
    const int l   = blockIdx.x;        // 0..639
    const int xcd = l & 7;
    const int w   = l >> 3;
    const int mt  = xcd * 16 + w / 5;
    const int nt  = w % 5;
    const int m0  = mt * 128;
    const int n0  = nt * 128;
    const int wm  = (wave >> 1) * 64;
    const int wn  = (wave & 1) * 64;

    char* ldsb = (char*)lds_s;

    // ---- staging addresses ----
    // A: thread covers row r = tid>>1, k-halfstep hh = tid&1 (16 consecutive floats).
    const int r  = tid >> 1;
    const int hh = tid & 1;
    const float* gA = X + (size_t)(m0 + r) * CC + hh * 16;
    // frag-major A write: unit = r>>4; l = (r&15) + (2*hh + c)*16, c in {0,1}
    const int wAoff = (r >> 4) * 1024 + (r & 15) * 16 + hh * 512;
    // B: wave stages local units 2w, 2w+1 (each 1KB linear in B2F)
    const unsigned short* gB0 = B2F + (size_t)((nt * 8 + 2 * wave) * 32) * 512 + lane * 8;
    const unsigned short* gB1 = B2F + (size_t)((nt * 8 + 2 * wave + 1) * 32) * 512 + lane * 8;
    const int u0off = 8192 + (2 * wave) * 1024;
    const int u1off = u0off + 1024;
    // frag read offsets (within a buffer)
    const int aoff = (wm >> 4) * 1024 + lane * 16;
    const int boff = 8192 + (wn >> 4) * 1024 + lane * 16;

    f32x4 acc[4][4] = {};
    float4 fa0, fa1, fa2, fa3;

#define CVTPK(d, lo, hi) asm("v_cvt_pk_bf16_f32 %0, %1, %2" : "=v"(d) : "v"(lo), "v"(hi))

#define STAGE_ISSUE(T, BB)                                                               \
    {                                                                                    \
        const float* ga_ = gA + (size_t)(T) * 32;                                        \
        fa0 = *(const float4*)(ga_);                                                     \
        fa1 = *(const float4*)(ga_ + 4);                                                 \
        fa2 = *(const float4*)(ga_ + 8);                                                 \
        fa3 = *(const float4*)(ga_ + 12);                                                \
        __builtin_amdgcn_global_load_lds(                                                \
            (const __attribute__((address_space(1))) void*)(gB0 + (size_t)(T) * 512),    \
            (__attribute__((address_space(3))) void*)(ldsb + (BB) + u0off), 16, 0, 0);   \
        __builtin_amdgcn_global_load_lds(                                                \
            (const __attribute__((address_space(1))) void*)(gB1 + (size_t)(T) * 512),    \
            (__attribute__((address_space(3))) void*)(ldsb + (BB) + u1off), 16, 0, 0);   \
    }

#define STAGE_WRITE(BB)                                                                  \
    {                                                                                    \
        unsigned int c0, c1, c2, c3, c4, c5, c6, c7;                                     \
        CVTPK(c0, fa0.x, fa0.y); CVTPK(c1, fa0.z, fa0.w);                                \
        CVTPK(c2, fa1.x, fa1.y); CVTPK(c3, fa1.z, fa1.w);                                \
        CVTPK(c4, fa2.x, fa2.y); CVTPK(c5, fa2.z, fa2.w);                                \
        CVTPK(c6, fa3.x, fa3.y); CVTPK(c7, fa3.z, fa3.w);                                \
        *(int4*)(ldsb + (BB) + wAoff)       = make_int4((int)c0, (int)c1, (int)c2, (int)c3); \
        *(int4*)(ldsb + (BB) + wAoff + 256) = make_int4((int)c4, (int)c5, (int)c6, (int)c7); \
    }

#define COMPUTE(BB)                                                                      \
    {                                                                                    \
        short8 af[4], bfr[4];                                                            \
        _Pragma("unroll")                                                                \
        for (int t = 0; t < 4; t++) {                                                    \
            af[t]  = *(const short8*)(ldsb + (BB) + aoff + t * 1024);                    \
            bfr[t] = *(const short8*)(ldsb + (BB) + boff + t * 1024);                    \
        }                                                                                \
        _Pragma("unroll")                                                                \
        for (int ti = 0; ti < 4; ti++)                                                   \
            _Pragma("unroll")                                                            \
            for (int tj = 0; tj < 4; tj++)                                               \
                acc[ti][tj] = __builtin_amdgcn_mfma_f32_16x16x32_bf16(                   \
                    af[ti], bfr[tj], acc[ti][tj], 0, 0, 0);                              \
    }

    // ---- prologue: stage step 0 into buf0; zero-fill overlapped with load latency ----
    STAGE_ISSUE(0, 0)
    {
        int base = l * ZPB;
        f32x4 z = {0.f, 0.f, 0.f, 0.f};
        for (int j = 0; j < 13; j++) {
            int o = j * 256 + tid;
            int idx = base + o;
            if (o < ZPB && idx < OUT4)
                __builtin_nontemporal_store(z, (f32x4*)out + idx);
        }
    }
    STAGE_WRITE(0)
    asm volatile("s_waitcnt vmcnt(0)" ::: "memory");
    __syncthreads();

    // ---- K-loop: 32 steps of K=32, double-buffered, 1 barrier/step ----
    for (int it = 0; it < 16; it++) {
        STAGE_ISSUE(2 * it + 1, 16384)
        COMPUTE(0)
        STAGE_WRITE(16384)
        asm volatile("s_waitcnt vmcnt(0)" ::: "memory");
        __syncthreads();
        if (it < 15) {
            STAGE_ISSUE(2 * it + 2, 0)
            COMPUTE(16384)
            STAGE_WRITE(0)
            asm volatile("s_waitcnt vmcnt(0)" ::: "memory");
        } else {
            COMPUTE(16384)
        }
        __syncthreads();
    }

#undef COMPUTE
#undef STAGE_WRITE
#undef STAGE_ISSUE
#undef CVTPK

    // ---- epilogue: block max of approx logits ----
    // C/D layout (16x16x32): col = lane&15, row = (lane>>4)*4 + reg
    float bias4[4];
#pragma unroll
    for (int tj = 0; tj < 4; tj++) bias4[tj] = bias[n0 + wn + tj * 16 + (lane & 15)];

    float vmax = -3.0e38f;
#pragma unroll
    for (int ti = 0; ti < 4; ti++)
#pragma unroll
        for (int tj = 0; tj < 4; tj++)
#pragma unroll
            for (int rr = 0; rr < 4; rr++)
                vmax = fmaxf(vmax, acc[ti][tj][rr] + bias4[tj]);
#pragma unroll
    for (int off = 32; off > 0; off >>= 1)
        vmax = fmaxf(vmax, __shfl_down(vmax, off, 64));
    if (lane == 0) redf[wave] = vmax;
    if (tid == 0) cnt_s = 0;
    __syncthreads();
    float bm = fmaxf(fmaxf(redf[0], redf[1]), fmaxf(redf[2], redf[3]));
    float thresh = bm - MARGIN;

    // ---- collect candidates within MARGIN of block max ----
#pragma unroll
    for (int ti = 0; ti < 4; ti++) {
#pragma unroll
        for (int rr = 0; rr < 4; rr++) {
            int m = m0 + wm + ti * 16 + (lane >> 4) * 4 + rr;
#pragma unroll
            for (int tj = 0; tj < 4; tj++) {
                float v = acc[ti][tj][rr] + bias4[tj];
                if (v >= thresh) {
                    int n = n0 + wn + tj * 16 + (lane & 15);
                    int idx = atomicAdd(&cnt_s, 1);
                    if (idx < 128) cand_s[idx] = (m << 10) | n;
                }
            }
        }
    }
    __syncthreads();
    int cnt = cnt_s < 128 ? cnt_s : 128;

    // ---- exact fp32 refine of each candidate (cooperative 1024-dot) ----
    for (int i = 0; i < cnt; i++) {
        int mc = cand_s[i] >> 10;
        int nc = cand_s[i] & 1023;
        float4 xv = *(const float4*)(X + (size_t)mc * CC + tid * 4);
        float4 wv = *(const float4*)(W + (size_t)nc * CC + tid * 4);
        float p = xv.x * wv.x + xv.y * wv.y + xv.z * wv.z + xv.w * wv.w;
#pragma unroll
        for (int off = 32; off > 0; off >>= 1) p += __shfl_down(p, off, 64);
        if (lane == 0) redf[wave] = p;
        __syncthreads();
        if (tid == 0) {
            float tot = redf[0] + redf[1] + redf[2] + redf[3] + bias[nc];
            unsigned int c = (unsigned int)((mc & 1023) * KN + nc);
            unsigned long long pk =
                ((unsigned long long)f32_orderable(tot) << 32) |
                (unsigned long long)(~c);
            atomicMax(slots + (mc >> 10), pk);
        }
        __syncthreads();
    }

    if (tid == 0) {
        __threadfence();
        done_s = atomicAdd(counter, 1u);
    }
    __syncthreads();

    // ---- last block scatters the 16 codebook rows ----
    if (done_s == NBLK - 1) {
        if (tid < 16) s16[tid] = atomicAdd(slots + tid, 0ull);   // coherent cross-XCD read
        __syncthreads();
        int rr  = tid >> 4;
        int seg = tid & 15;
        unsigned long long p = s16[rr];
        unsigned int c = ~(unsigned int)(p & 0xFFFFFFFFull);
        int tl = (int)(c / KN);
        int kg = (int)(c % KN);
        int b  = rr >> 1, h = rr & 1;
        int nstar = b * 2048 + h * 1024 + tl;
        int g = kg / EE;
        const float4* src = (const float4*)(codebook + (size_t)kg * DD) + seg * 4;
        float4* dst = (float4*)(out + (size_t)nstar * 512 + (size_t)g * DD) + seg * 4;
#pragma unroll
        for (int j = 0; j < 4; j++) dst[j] = src[j];
    }
}

// ------------------- fallback-only kernels (ws too small; not used in practice) ------------
__global__ __launch_bounds__(256)
void zs_kernel(const unsigned long long* __restrict__ slots,
               const float* __restrict__ codebook,
               float4* __restrict__ out4) {
    int i4 = blockIdx.x * 256 + threadIdx.x;
    int n  = i4 >> 7;
    int c4 = i4 & 127;
    int b  = n >> 11;
    int h  = (n >> 10) & 1;
    unsigned long long p = slots[b * 2 + h];
    unsigned int c = ~(unsigned int)(p & 0xFFFFFFFFull);
    int tl = (int)(c / KN);
    int kg = (int)(c % KN);
    int nstar = b * 2048 + h * 1024 + tl;
    int g = kg / EE;
    float4 v = make_float4(0.f, 0.f, 0.f, 0.f);
    if (n == nstar && (c4 >> 6) == g)
        v = ((const float4*)codebook)[kg * 64 + (c4 & 63)];
    out4[i4] = v;
}

#define BM 128
#define BN 64
#define BK 32
#define LDA (BM + 4)
#define LDB (BN + 4)

__global__ __launch_bounds__(128)
void gemm_argmax_f32(const float* __restrict__ X, const float* __restrict__ W,
                     const float* __restrict__ bias,
                     unsigned long long* __restrict__ slots) {
    __shared__ float Asf[BK][LDA];
    __shared__ float Bsf[BK][LDB];
    const int tid = threadIdx.x;
    const int m0 = blockIdx.y * BM;
    const int n0 = blockIdx.x * BN;
    const int tx = tid & 7, ty = tid >> 3;
    float acc[8][8];
#pragma unroll
    for (int i = 0; i < 8; i++)
#pragma unroll
        for (int j = 0; j < 8; j++) acc[i][j] = 0.0f;
    const int lm = tid >> 3, lk = (tid & 7) * 4;
    const float* Xb = X + (size_t)m0 * CC;
    const float* Wb = W + (size_t)n0 * CC;
    for (int k0 = 0; k0 < CC; k0 += BK) {
#pragma unroll
        for (int rr = 0; rr < 8; rr++) {
            int m = rr * 16 + lm;
            float4 v = *(const float4*)(Xb + (size_t)m * CC + k0 + lk);
            Asf[lk + 0][m] = v.x; Asf[lk + 1][m] = v.y; Asf[lk + 2][m] = v.z; Asf[lk + 3][m] = v.w;
        }
#pragma unroll
        for (int rr = 0; rr < 4; rr++) {
            int m = rr * 16 + lm;
            float4 v = *(const float4*)(Wb + (size_t)m * CC + k0 + lk);
            Bsf[lk + 0][m] = v.x; Bsf[lk + 1][m] = v.y; Bsf[lk + 2][m] = v.z; Bsf[lk + 3][m] = v.w;
        }
        __syncthreads();
#pragma unroll
        for (int kk = 0; kk < BK; kk++) {
            float4 A0 = *(const float4*)&Asf[kk][ty * 8];
            float4 A1 = *(const float4*)&Asf[kk][ty * 8 + 4];
            float4 B0 = *(const float4*)&Bsf[kk][tx * 8];
            float4 B1 = *(const float4*)&Bsf[kk][tx * 8 + 4];
            float a[8] = {A0.x, A0.y, A0.z, A0.w, A1.x, A1.y, A1.z, A1.w};
            float b[8] = {B0.x, B0.y, B0.z, B0.w, B1.x, B1.y, B1.z, B1.w};
#pragma unroll
            for (int i = 0; i < 8; i++)
#pragma unroll
                for (int j = 0; j < 8; j++) acc[i][j] = fmaf(a[i], b[j], acc[i][j]);
        }
        __syncthreads();
    }
    unsigned long long best = 0ull;
#pragma unroll
    for (int i = 0; i < 8; i++) {
        int mg = m0 + ty * 8 + i;
        int tl = mg & 1023;
#pragma unroll
        for (int j = 0; j < 8; j++) {
            int kg = n0 + tx * 8 + j;
            float v = acc[i][j] + bias[kg];
            unsigned int c = (unsigned int)(tl * KN + kg);
            unsigned long long p = ((unsigned long long)f32_orderable(v) << 32) |
                                   (unsigned long long)(~c);
            if (p > best) best = p;
        }
    }
#pragma unroll
    for (int off = 32; off > 0; off >>= 1) {
        unsigned long long o = __shfl_down(best, off, 64);
        if (o > best) best = o;
    }
    __shared__ unsigned long long red2[2];
    if ((tid & 63) == 0) red2[tid >> 6] = best;
    __syncthreads();
    if (tid == 0) {
        unsigned long long b0 = red2[0], b1 = red2[1];
        atomicMax(slots + (m0 >> 10), b0 > b1 ? b0 : b1);
    }
}

extern "C" void kernel_launch(void* const* d_in, const int* in_sizes, int n_in,
                              void* d_out, int out_size, void* d_ws, size_t ws_size,
                              hipStream_t stream) {
    const float* X        = (const float*)d_in[0];  // (8,2048,1024)
    const float* W        = (const float*)d_in[1];  // (640,1024)
    const float* bias     = (const float*)d_in[2];  // (640,)
    const float* codebook = (const float*)d_in[3];  // (640,256)
    float* out = (float*)d_out;                     // (8,2048,512) fp32

    unsigned long long* slots = (unsigned long long*)d_ws;   // [0..15] slots, [16] counter
    unsigned int* counter = (unsigned int*)(slots + 16);
    const size_t B_off   = 256;
    const size_t B_bytes = (size_t)KN * CC * 2;     // 1,310,720 (bf16 frag-major W)
    const size_t need = B_off + B_bytes;

    if (ws_size >= need) {
        unsigned short* B2F = (unsigned short*)((char*)d_ws + B_off);
        hipLaunchKernelGGL(prep_kernel, dim3(320), dim3(256), 0, stream, W, B2F, slots);
        hipLaunchKernelGGL(vq_fused, dim3(NBLK), dim3(256), 0, stream,
                           X, B2F, W, bias, codebook, out, slots, counter);
    } else {
        hipLaunchKernelGGL(init_slots_kernel, dim3(1), dim3(64), 0, stream, slots);
        hipLaunchKernelGGL(gemm_argmax_f32, dim3(KN / BN, MTOT / BM), dim3(128), 0, stream,
                           X, W, bias, slots);
        hipLaunchKernelGGL(zs_kernel, dim3(OUT4 / 256), dim3(256), 0, stream,
                           slots, codebook, (float4*)out);
    }
}